// Round 2
// baseline (682.941 us; speedup 1.0000x reference)
//
#include <hip/hip_runtime.h>

#define NSEG 6
#define NBLOCKS 2048
#define NTHREADS 256
#define LDS_STRIDE 257              // odd stride -> bank (s+t)%32, conflict-free
#define CNT_BYTE_OFF (NSEG * LDS_STRIDE)   // dword offset of count table

__global__ __launch_bounds__(NTHREADS) void wdice_partial(
    const float4* __restrict__ pred,
    const int4* __restrict__ tgt,
    const int4* __restrict__ wt,
    int nvec,
    float* __restrict__ out_ws)     // [NBLOCKS][12]: 6 psum then 6 cnt
{
    __shared__ float acc[12 * LDS_STRIDE];

    int tid = threadIdx.x;
    // zero LDS
    for (int k = tid; k < 12 * LDS_STRIDE; k += NTHREADS) acc[k] = 0.f;
    __syncthreads();

    int gtid = blockIdx.x * NTHREADS + tid;
    int stride = gridDim.x * NTHREADS;

    for (int base = gtid; base < nvec; base += 2 * stride) {
        int i0 = base;
        int i1 = base + stride;
        bool has1 = i1 < nvec;

        float4 p0 = pred[i0];
        int4 t0 = tgt[i0];
        int4 w0 = wt[i0];
        float4 p1, pz = make_float4(0.f, 0.f, 0.f, 0.f);
        int4 t1 = make_int4(0, 0, 0, 0), w1 = t1;
        if (has1) { p1 = pred[i1]; t1 = tgt[i1]; w1 = wt[i1]; } else { p1 = pz; }

        // group 0
        {
            int s0 = t0.x * 3 + w0.x;
            int s1 = t0.y * 3 + w0.y;
            int s2 = t0.z * 3 + w0.z;
            int s3 = t0.w * 3 + w0.w;
            atomicAdd(&acc[s0 * LDS_STRIDE + tid], p0.x);
            atomicAdd(&acc[s0 * LDS_STRIDE + tid + CNT_BYTE_OFF], 1.f);
            atomicAdd(&acc[s1 * LDS_STRIDE + tid], p0.y);
            atomicAdd(&acc[s1 * LDS_STRIDE + tid + CNT_BYTE_OFF], 1.f);
            atomicAdd(&acc[s2 * LDS_STRIDE + tid], p0.z);
            atomicAdd(&acc[s2 * LDS_STRIDE + tid + CNT_BYTE_OFF], 1.f);
            atomicAdd(&acc[s3 * LDS_STRIDE + tid], p0.w);
            atomicAdd(&acc[s3 * LDS_STRIDE + tid + CNT_BYTE_OFF], 1.f);
        }
        // group 1
        if (has1) {
            int s0 = t1.x * 3 + w1.x;
            int s1 = t1.y * 3 + w1.y;
            int s2 = t1.z * 3 + w1.z;
            int s3 = t1.w * 3 + w1.w;
            atomicAdd(&acc[s0 * LDS_STRIDE + tid], p1.x);
            atomicAdd(&acc[s0 * LDS_STRIDE + tid + CNT_BYTE_OFF], 1.f);
            atomicAdd(&acc[s1 * LDS_STRIDE + tid], p1.y);
            atomicAdd(&acc[s1 * LDS_STRIDE + tid + CNT_BYTE_OFF], 1.f);
            atomicAdd(&acc[s2 * LDS_STRIDE + tid], p1.z);
            atomicAdd(&acc[s2 * LDS_STRIDE + tid + CNT_BYTE_OFF], 1.f);
            atomicAdd(&acc[s3 * LDS_STRIDE + tid], p1.w);
            atomicAdd(&acc[s3 * LDS_STRIDE + tid + CNT_BYTE_OFF], 1.f);
        }
    }

    __syncthreads();

    // wave 0 reduces all 12 rows of 256 values
    if (tid < 64) {
        for (int r = 0; r < 12; ++r) {
            float v = acc[r * LDS_STRIDE + tid]
                    + acc[r * LDS_STRIDE + tid + 64]
                    + acc[r * LDS_STRIDE + tid + 128]
                    + acc[r * LDS_STRIDE + tid + 192];
#pragma unroll
            for (int off = 32; off > 0; off >>= 1)
                v += __shfl_down(v, off, 64);
            if (tid == 0) out_ws[blockIdx.x * 12 + r] = v;
        }
    }
}

__global__ __launch_bounds__(NTHREADS) void wdice_final(
    const float* __restrict__ ws,   // [nrows][12]
    int nrows,
    float* __restrict__ out)
{
    double a[12];
#pragma unroll
    for (int r = 0; r < 12; ++r) a[r] = 0.0;

    for (int row = threadIdx.x; row < nrows; row += blockDim.x) {
#pragma unroll
        for (int r = 0; r < 12; ++r)
            a[r] += (double)ws[row * 12 + r];
    }

#pragma unroll
    for (int r = 0; r < 12; ++r) {
#pragma unroll
        for (int off = 32; off > 0; off >>= 1)
            a[r] += __shfl_down(a[r], off, 64);
    }

    __shared__ double l[4][12];
    int lane = threadIdx.x & 63;
    int wave = threadIdx.x >> 6;
    if (lane == 0) {
#pragma unroll
        for (int r = 0; r < 12; ++r) l[wave][r] = a[r];
    }
    __syncthreads();
    if (threadIdx.x == 0) {
        double numer = 0.0, denom = 0.0;
#pragma unroll
        for (int s = 0; s < NSEG; ++s) {
            double tps = l[0][s] + l[1][s] + l[2][s] + l[3][s];
            double tcn = l[0][s + 6] + l[1][s + 6] + l[2][s + 6] + l[3][s + 6];
            if (tcn > 0.0) {
                double inv_n2 = 1.0 / (tcn * tcn);
                numer += tps * inv_n2;
                denom += (tps + tcn) * inv_n2;
            }
        }
        out[0] = (float)(1.0 - 2.0 * numer / denom);
    }
}

extern "C" void kernel_launch(void* const* d_in, const int* in_sizes, int n_in,
                              void* d_out, int out_size, void* d_ws, size_t ws_size,
                              hipStream_t stream) {
    const float4* pred = (const float4*)d_in[0];
    const int4* tgt = (const int4*)d_in[1];
    const int4* wt = (const int4*)d_in[2];
    int n = in_sizes[0];
    int nvec = n / 4;

    float* ws = (float*)d_ws;  // NBLOCKS * 12 floats

    wdice_partial<<<NBLOCKS, NTHREADS, 0, stream>>>(pred, tgt, wt, nvec, ws);
    wdice_final<<<1, NTHREADS, 0, stream>>>(ws, NBLOCKS, (float*)d_out);
}

// Round 3
// 152.516 us; speedup vs baseline: 4.4778x; 4.4778x over previous
//
#include <hip/hip_runtime.h>

#define NSEG 6
#define NBLOCKS 2048
#define NTHREADS 256

__device__ __forceinline__ void proc4(const float4& p, const int4& t, const int4& w,
                                      float ps[NSEG], unsigned long long& c64) {
    int s0 = t.x * 3 + w.x;
    int s1 = t.y * 3 + w.y;
    int s2 = t.z * 3 + w.z;
    int s3 = t.w * 3 + w.w;
    c64 += (1ull << (s0 << 3)) + (1ull << (s1 << 3)) +
           (1ull << (s2 << 3)) + (1ull << (s3 << 3));
#pragma unroll
    for (int s = 0; s < NSEG; ++s) {
        float v = (s0 == s ? p.x : 0.f);
        v += (s1 == s ? p.y : 0.f);
        v += (s2 == s ? p.z : 0.f);
        v += (s3 == s ? p.w : 0.f);
        ps[s] += v;
    }
}

__global__ __launch_bounds__(NTHREADS) void wdice_partial(
    const float4* __restrict__ pred,
    const int4* __restrict__ tgt,
    const int4* __restrict__ wt,
    int nvec,
    float* __restrict__ out_ws)     // [NBLOCKS][12]: 6 psum then 6 cnt
{
    float ps[NSEG];
    int cn[NSEG];
#pragma unroll
    for (int s = 0; s < NSEG; ++s) { ps[s] = 0.f; cn[s] = 0; }

    const int tid = threadIdx.x;
    const int stride = NBLOCKS * NTHREADS;
    int i = blockIdx.x * NTHREADS + tid;

    // main loop: 4-deep batched loads; packed 8-bit count fields, flushed
    // every <=15 iterations (15*16=240 <= 255, no field overflow)
    while (i + 3 * stride < nvec) {
        unsigned long long c64 = 0ull;
        for (int chunk = 0; chunk < 15 && i + 3 * stride < nvec; ++chunk, i += 4 * stride) {
            float4 p0 = pred[i];
            float4 p1 = pred[i + stride];
            float4 p2 = pred[i + 2 * stride];
            float4 p3 = pred[i + 3 * stride];
            int4 t0 = tgt[i];
            int4 t1 = tgt[i + stride];
            int4 t2 = tgt[i + 2 * stride];
            int4 t3 = tgt[i + 3 * stride];
            int4 w0 = wt[i];
            int4 w1 = wt[i + stride];
            int4 w2 = wt[i + 2 * stride];
            int4 w3 = wt[i + 3 * stride];

            proc4(p0, t0, w0, ps, c64);
            proc4(p1, t1, w1, ps, c64);
            proc4(p2, t2, w2, ps, c64);
            proc4(p3, t3, w3, ps, c64);
        }
#pragma unroll
        for (int s = 0; s < NSEG; ++s) cn[s] += (int)((c64 >> (8 * s)) & 0xFFull);
    }
    // tail (not executed for the benchmark shape: nvec divisible by 4*stride)
    for (; i < nvec; i += stride) {
        float4 p = pred[i];
        int4 t = tgt[i];
        int4 w = wt[i];
        int s0 = t.x * 3 + w.x;
        int s1 = t.y * 3 + w.y;
        int s2 = t.z * 3 + w.z;
        int s3 = t.w * 3 + w.w;
#pragma unroll
        for (int s = 0; s < NSEG; ++s) {
            cn[s] += (s0 == s) + (s1 == s) + (s2 == s) + (s3 == s);
            float v = (s0 == s ? p.x : 0.f);
            v += (s1 == s ? p.y : 0.f);
            v += (s2 == s ? p.z : 0.f);
            v += (s3 == s ? p.w : 0.f);
            ps[s] += v;
        }
    }

    // pack counts into 16-bit fields: per-thread <=128, wave sum <=8192,
    // block sum <=32768 -- no overflow
    unsigned int pk0 = (unsigned)cn[0] | ((unsigned)cn[1] << 16);
    unsigned int pk1 = (unsigned)cn[2] | ((unsigned)cn[3] << 16);
    unsigned int pk2 = (unsigned)cn[4] | ((unsigned)cn[5] << 16);

    // wave (64-lane) shuffle reduction: 6 floats + 3 packed uints
#pragma unroll
    for (int off = 32; off > 0; off >>= 1) {
#pragma unroll
        for (int s = 0; s < NSEG; ++s) ps[s] += __shfl_down(ps[s], off, 64);
        pk0 += __shfl_down(pk0, off, 64);
        pk1 += __shfl_down(pk1, off, 64);
        pk2 += __shfl_down(pk2, off, 64);
    }

    __shared__ float lps[4][NSEG];
    __shared__ unsigned int lpk[4][3];
    int lane = tid & 63;
    int wave = tid >> 6;
    if (lane == 0) {
#pragma unroll
        for (int s = 0; s < NSEG; ++s) lps[wave][s] = ps[s];
        lpk[wave][0] = pk0; lpk[wave][1] = pk1; lpk[wave][2] = pk2;
    }
    __syncthreads();
    if (tid == 0) {
        unsigned int bk0 = lpk[0][0] + lpk[1][0] + lpk[2][0] + lpk[3][0];
        unsigned int bk1 = lpk[0][1] + lpk[1][1] + lpk[2][1] + lpk[3][1];
        unsigned int bk2 = lpk[0][2] + lpk[1][2] + lpk[2][2] + lpk[3][2];
#pragma unroll
        for (int s = 0; s < NSEG; ++s) {
            float tps = lps[0][s] + lps[1][s] + lps[2][s] + lps[3][s];
            out_ws[blockIdx.x * 12 + s] = tps;
        }
        out_ws[blockIdx.x * 12 + 6]  = (float)(bk0 & 0xFFFF);
        out_ws[blockIdx.x * 12 + 7]  = (float)(bk0 >> 16);
        out_ws[blockIdx.x * 12 + 8]  = (float)(bk1 & 0xFFFF);
        out_ws[blockIdx.x * 12 + 9]  = (float)(bk1 >> 16);
        out_ws[blockIdx.x * 12 + 10] = (float)(bk2 & 0xFFFF);
        out_ws[blockIdx.x * 12 + 11] = (float)(bk2 >> 16);
    }
}

__global__ __launch_bounds__(NTHREADS) void wdice_final(
    const float* __restrict__ ws,   // [nrows][12]
    int nrows,
    float* __restrict__ out)
{
    double a[12];
#pragma unroll
    for (int r = 0; r < 12; ++r) a[r] = 0.0;

    for (int row = threadIdx.x; row < nrows; row += blockDim.x) {
#pragma unroll
        for (int r = 0; r < 12; ++r)
            a[r] += (double)ws[row * 12 + r];
    }

#pragma unroll
    for (int r = 0; r < 12; ++r) {
#pragma unroll
        for (int off = 32; off > 0; off >>= 1)
            a[r] += __shfl_down(a[r], off, 64);
    }

    __shared__ double l[4][12];
    int lane = threadIdx.x & 63;
    int wave = threadIdx.x >> 6;
    if (lane == 0) {
#pragma unroll
        for (int r = 0; r < 12; ++r) l[wave][r] = a[r];
    }
    __syncthreads();
    if (threadIdx.x == 0) {
        double numer = 0.0, denom = 0.0;
#pragma unroll
        for (int s = 0; s < NSEG; ++s) {
            double tps = l[0][s] + l[1][s] + l[2][s] + l[3][s];
            double tcn = l[0][s + 6] + l[1][s + 6] + l[2][s + 6] + l[3][s + 6];
            if (tcn > 0.0) {
                double inv_n2 = 1.0 / (tcn * tcn);
                numer += tps * inv_n2;
                denom += (tps + tcn) * inv_n2;
            }
        }
        out[0] = (float)(1.0 - 2.0 * numer / denom);
    }
}

extern "C" void kernel_launch(void* const* d_in, const int* in_sizes, int n_in,
                              void* d_out, int out_size, void* d_ws, size_t ws_size,
                              hipStream_t stream) {
    const float4* pred = (const float4*)d_in[0];
    const int4* tgt = (const int4*)d_in[1];
    const int4* wt = (const int4*)d_in[2];
    int n = in_sizes[0];
    int nvec = n / 4;

    float* ws = (float*)d_ws;  // NBLOCKS * 12 floats

    wdice_partial<<<NBLOCKS, NTHREADS, 0, stream>>>(pred, tgt, wt, nvec, ws);
    wdice_final<<<1, NTHREADS, 0, stream>>>(ws, NBLOCKS, (float*)d_out);
}